// Round 12
// baseline (405.315 us; speedup 1.0000x reference)
//
#include <hip/hip_runtime.h>
#include <hip/hip_bf16.h>

#define VSZ   32000
#define EMBD  512
#define HIDD  1024
#define BB    64
#define TSEQ  512
#define G4    4096

typedef short bf16x8 __attribute__((ext_vector_type(8)));
typedef float f32x4  __attribute__((ext_vector_type(4)));

typedef __attribute__((address_space(3))) unsigned       lds_u32_t;
typedef __attribute__((address_space(1))) const unsigned glb_u32_t;
__device__ __forceinline__ void gload16(const void* g, void* l){
  __builtin_amdgcn_global_load_lds((glb_u32_t*)g, (lds_u32_t*)l, 16, 0, 0);
}

__device__ __forceinline__ float sigmoid_f(float x){ return 1.0f/(1.0f+__expf(-x)); }
__device__ __forceinline__ float fast_tanh(float x){
  float e = __expf(2.0f*x);
  return 1.0f - 2.0f*__builtin_amdgcn_rcpf(e + 1.0f);
}
__device__ __forceinline__ short f2bfs(float x){
  unsigned u = __float_as_uint(x);
  unsigned r = (u + 0x7FFFu + ((u>>16)&1u)) >> 16;
  return (short)r;
}
__device__ __forceinline__ float bf2f(short s){
  return __uint_as_float(((unsigned)(unsigned short)s) << 16);
}
// single-instr packed f32x2 -> bf16x2 (RNE), gfx950
__device__ __forceinline__ unsigned cvtpk(float a, float b){
  unsigned r;
  asm("v_cvt_pk_bf16_f32 %0, %1, %2" : "=v"(r) : "v"(a), "v"(b));
  return r;
}
__device__ __forceinline__ bf16x8 cvt8(float4 a, float4 b){
  union { unsigned u[4]; bf16x8 v; } o;
  o.u[0]=cvtpk(a.x,a.y); o.u[1]=cvtpk(a.z,a.w);
  o.u[2]=cvtpk(b.x,b.y); o.u[3]=cvtpk(b.z,b.w);
  return o.v;
}
__device__ __forceinline__ float wave_sum(float x){
  #pragma unroll
  for (int off=32; off>0; off>>=1) x += __shfl_xor(x, off);
  return x;
}
__device__ __forceinline__ float wave_max(float x){
  #pragma unroll
  for (int off=32; off>0; off>>=1) x = fmaxf(x, __shfl_xor(x, off));
  return x;
}

// ---------------- merged prep: pack Wk_e/Wk_b + cvt keys + prep_h + emb gather ----------------
// [0,512): pack Wk_e; [512,1024): pack Wk_b; [1024,33792): cvtkeys;
// [33792,33824): h -> xb[:,2560:3584]; [33824,33840): emb -> xb[:,0:512].
__global__ __launch_bounds__(256) void k_prep_all(
    const float* __restrict__ Wk_e, const float* __restrict__ Wk_b,
    const float* __restrict__ enc,  const float* __restrict__ bwd,
    const float* __restrict__ h,
    const float* __restrict__ tab,  const int* __restrict__ y,
    short* __restrict__ pk_e, short* __restrict__ pk_b,
    short* __restrict__ pkeys, short* __restrict__ xb){
  int bid = blockIdx.x;
  if (bid < 1024){
    const float* Wk = (bid < 512) ? Wk_e : Wk_b;
    short* dst      = (bid < 512) ? pk_e : pk_b;
    int id = (bid & 511)*256 + threadIdx.x;   // 131072 = 1024a * 128g
    int a = id >> 7, g = id & 127;
    int gs = (g & ~7) | ((g & 7) ^ (a & 7));
    const float* src = Wk + (size_t)a*1024 + gs*8;
    float4 f0 = ((const float4*)src)[0], f1 = ((const float4*)src)[1];
    *(bf16x8*)(dst + (size_t)id*8) = cvt8(f0, f1);
  } else if (bid < 33792){
    int r = bid - 1024;                       // 0..32767
    int att = r >> 14;
    const float* src0 = att ? bwd : enc;
    int id = (r & 16383)*256 + threadIdx.x;   // 4194304 = 32768bt * 128g
    int g = id & 127, bt = id >> 7;
    int t = bt & 511;
    int gs = (g & ~7) | ((g & 7) ^ (t & 7));
    const float* sp = src0 + (size_t)bt*1024 + gs*8;
    float4 f0 = ((const float4*)sp)[0], f1 = ((const float4*)sp)[1];
    *(bf16x8*)(pkeys + (((size_t)att*32768 + bt)*128 + g)*8) = cvt8(f0, f1);
  } else if (bid < 33824){
    int id = (bid - 33792)*256 + threadIdx.x; // 8192
    int b = id >> 7, d = (id & 127)*8;
    const float4* s = (const float4*)(h + (size_t)b*HIDD + d);
    *(bf16x8*)(xb + (size_t)b*3584 + 2560 + d) = cvt8(s[0], s[1]);
  } else {
    int id = (bid - 33824)*256 + threadIdx.x; // 4096 = 64b * 64g
    int b = id >> 6, d = (id & 63)*8;
    const float* src = tab + (size_t)y[b]*EMBD + d;
    float4 f0 = ((const float4*)src)[0], f1 = ((const float4*)src)[1];
    *(bf16x8*)(xb + (size_t)b*3584 + d) = cvt8(f0, f1);
  }
}

// ---------------- generic M=64 MFMA GEMM with K-split partials ----------------
__global__ __launch_bounds__(256) void k_mm64(
    const short* __restrict__ A0, int lda0, const float* __restrict__ B0, int ldb0, int K0, float* __restrict__ out0, int ldo0,
    const short* __restrict__ A1, int lda1, const float* __restrict__ B1, int ldb1, int K1, float* __restrict__ out1, int ldo1){
  const short* A; const float* B; float* out; int lda, ldb, K, ldo;
  if (blockIdx.z == 0){ A=A0; B=B0; out=out0; lda=lda0; ldb=ldb0; K=K0; ldo=ldo0; }
  else                { A=A1; B=B1; out=out1; lda=lda1; ldb=ldb1; K=K1; ldo=ldo1; }
  int tid = threadIdx.x, l = tid & 63, w = tid >> 6;
  int l15 = l & 15, l4 = l >> 4;
  int n0 = blockIdx.x*256 + w*64;
  int kper = K / gridDim.y;
  int dbeg = blockIdx.y * kper, dend = dbeg + kper;
  f32x4 acc[4][4];
  #pragma unroll
  for (int i=0;i<4;i++)
    #pragma unroll
    for (int j=0;j<4;j++)
      #pragma unroll
      for (int r=0;r<4;r++) acc[i][j][r]=0.f;
  for (int d0=dbeg; d0<dend; d0+=32){
    bf16x8 af[4];
    #pragma unroll
    for (int ms=0; ms<4; ms++)
      af[ms] = *(const bf16x8*)(A + (size_t)(ms*16 + l15)*lda + d0 + l4*8);
    bf16x8 bfr[4];
    #pragma unroll
    for (int ni=0; ni<4; ni++){
      const float* bp = B + (size_t)(n0 + ni*16 + l15)*ldb + d0 + l4*8;
      float4 f0 = ((const float4*)bp)[0], f1 = ((const float4*)bp)[1];
      bfr[ni] = cvt8(f0, f1);
    }
    #pragma unroll
    for (int ms=0; ms<4; ms++)
      #pragma unroll
      for (int ni=0; ni<4; ni++)
        acc[ms][ni] = __builtin_amdgcn_mfma_f32_16x16x32_bf16(af[ms], bfr[ni], acc[ms][ni], 0,0,0);
  }
  float* op = out + (size_t)blockIdx.y * 64 * ldo;
  #pragma unroll
  for (int ms=0; ms<4; ms++)
    #pragma unroll
    for (int ni=0; ni<4; ni++)
      #pragma unroll
      for (int r=0; r<4; r++){
        int m = ms*16 + l4*4 + r;
        op[(size_t)m*ldo + n0 + ni*16 + l15] = acc[ms][ni][r];
      }
}

// ---------------- K3: energy 128x128x1024 GEMM, BOTH operands via global_load_lds ----------------
// (unchanged: 173 us, MfmaUtil 35%, conflicts 0 — m97-structure ceiling)
__global__ __launch_bounds__(256,3) void k_energy(
    const short* __restrict__ pkeys,
    const short* __restrict__ pke, const short* __restrict__ pkb,
    const float* __restrict__ qpe, const float* __restrict__ qpb,
    const float* __restrict__ ve, const float* __restrict__ vb,
    float* __restrict__ ep_out){                                   // [att][8][64][512]
  __shared__ short A_s[128*64];
  __shared__ short B_s[128*64];
  __shared__ float ebuf[2][128];

  int wg = blockIdx.x;
  int xcd = wg & 7, idx = wg >> 3;
  int tglob = xcd*64 + (idx >> 3);
  int A0 = idx & 7;
  int att = tglob >> 8;
  int tt  = tglob & 255;
  int b = tt >> 2, t0 = (tt & 3)*128;

  const short* pk = att ? pkb : pke;
  const float* qp = att ? qpb : qpe;
  const float* v  = att ? vb  : ve;

  int tid = threadIdx.x, l = tid & 63, w = tid >> 6;
  int l15 = l & 15, l4 = l >> 4;
  int wr = w >> 1, wc = w & 1;

  const char* asrc = (const char*)(pkeys + ((size_t)att*32768 + (size_t)b*512)*1024)
                   + (size_t)(t0 + w*32 + (l>>3))*2048 + (l&7)*16;
  const char* bsrc = (const char*)pk + (size_t)(A0*128 + w*32 + (l>>3))*2048 + (l&7)*16;

  f32x4 acc[4][4];
  #pragma unroll
  for (int i=0;i<4;i++)
    #pragma unroll
    for (int j=0;j<4;j++)
      #pragma unroll
      for (int r=0;r<4;r++) acc[i][j][r]=0.f;

  for (int c=0; c<16; ++c){
    if (c) __syncthreads();
    #pragma unroll
    for (int k=0;k<4;k++)
      gload16(asrc + (size_t)c*128 + (size_t)k*16384, (char*)A_s + w*4096 + k*1024);
    #pragma unroll
    for (int k=0;k<4;k++)
      gload16(bsrc + (size_t)c*128 + (size_t)k*16384, (char*)B_s + w*4096 + k*1024);
    __syncthreads();
    #pragma unroll
    for (int ks=0; ks<2; ks++){
      bf16x8 af[4], bf[4];
      #pragma unroll
      for (int ms=0; ms<4; ms++){
        int row = wr*64 + ms*16 + l15;
        af[ms] = *(const bf16x8*)((char*)A_s + row*128 + ((ks*64 + l4*16) ^ ((row&7)<<4)));
      }
      #pragma unroll
      for (int ni=0; ni<4; ni++){
        int row = wc*64 + ni*16 + l15;
        bf[ni] = *(const bf16x8*)((char*)B_s + row*128 + ((ks*64 + l4*16) ^ ((row&7)<<4)));
      }
      #pragma unroll
      for (int ms=0; ms<4; ms++)
        #pragma unroll
        for (int ni=0; ni<4; ni++)
          acc[ms][ni] = __builtin_amdgcn_mfma_f32_16x16x32_bf16(af[ms], bf[ni], acc[ms][ni], 0,0,0);
    }
  }

  float qv[4], vv[4];
  #pragma unroll
  for (int ni=0; ni<4; ni++){
    int a = A0*128 + wc*64 + ni*16 + l15;
    qv[ni] = qp[(size_t)b*HIDD + a] + qp[65536 + (size_t)b*HIDD + a];
    vv[ni] = v[a];
  }
  float es[16];
  #pragma unroll
  for (int ms=0; ms<4; ms++)
    #pragma unroll
    for (int r=0; r<4; r++){
      float s = 0.f;
      #pragma unroll
      for (int ni=0; ni<4; ni++)
        s += vv[ni]*fast_tanh(qv[ni] + acc[ms][ni][r]);
      es[ms*4+r] = s;
    }
  #pragma unroll
  for (int i=0;i<16;i++){
    float x = es[i];
    x += __shfl_xor(x,1); x += __shfl_xor(x,2);
    x += __shfl_xor(x,4); x += __shfl_xor(x,8);
    es[i] = x;
  }
  if (l15 == 0){
    #pragma unroll
    for (int ms=0; ms<4; ms++)
      #pragma unroll
      for (int r=0; r<4; r++)
        ebuf[wc][wr*64 + ms*16 + l4*4 + r] = es[ms*4+r];
  }
  __syncthreads();
  if (tid < 128)
    ep_out[(((size_t)att*8 + A0)*BB + b)*TSEQ + t0 + tid] = ebuf[0][tid] + ebuf[1][tid];
}

// ---------------- K4: softmax over T (sums 8 a-tile partials, applies mask) ----------------
__global__ __launch_bounds__(256) void k_softmax_t(const float* __restrict__ ep,
                                                   const int* __restrict__ mask,
                                                   float* __restrict__ att_e,
                                                   float* __restrict__ att_b){
  int b = blockIdx.x, att = blockIdx.y;
  float* e = (att ? att_b : att_e) + (size_t)b*TSEQ;
  __shared__ float red[8];
  int tid = threadIdx.x, lane = tid & 63, w = tid >> 6;
  float v0 = 0.f, v1 = 0.f;
  #pragma unroll
  for (int i=0;i<8;i++){
    const float* p = ep + (((size_t)att*8 + i)*BB + b)*TSEQ;
    v0 += p[tid]; v1 += p[tid+256];
  }
  if (att==0){
    if (mask[(size_t)b*TSEQ + tid]==0)      v0 = -3.4e38f;
    if (mask[(size_t)b*TSEQ + tid+256]==0)  v1 = -3.4e38f;
  }
  float m = wave_max(fmaxf(v0, v1));
  if (lane==0) red[w] = m;
  __syncthreads();
  m = fmaxf(fmaxf(red[0],red[1]), fmaxf(red[2],red[3]));
  float x0 = __expf(v0-m), x1 = __expf(v1-m);
  float s = wave_sum(x0+x1);
  if (lane==0) red[4+w] = s;
  __syncthreads();
  s = red[4]+red[5]+red[6]+red[7];
  float inv = 1.0f/s;
  e[tid] = x0*inv; e[tid+256] = x1*inv;
}

// ---------------- K5: context = attn @ keys, reading packed bf16 keys ----------------
__global__ __launch_bounds__(256) void k_ctx(const short* __restrict__ pkeys,
                                             const float* __restrict__ att_e,
                                             const float* __restrict__ att_b,
                                             float* __restrict__ ctxp){
  int b = blockIdx.x, sel = blockIdx.y, s = blockIdx.z;
  const short* base = pkeys + (((size_t)sel*32768) + (size_t)b*512 + s*64)*1024;
  const float* att  = (sel ? att_b : att_e) + (size_t)b*TSEQ + s*64;
  int g = threadIdx.x & 127, th = threadIdx.x >> 7;
  const short* rp = base + (size_t)th*32*1024;
  float acc[8];
  #pragma unroll
  for (int j=0;j<8;j++) acc[j]=0.f;
  for (int t=0;t<32;t++){
    float a = att[th*32 + t];
    int gg = (g & ~7) | ((g & 7) ^ (t & 7));
    bf16x8 kv = *(const bf16x8*)(rp + (size_t)t*1024 + gg*8);
    #pragma unroll
    for (int j=0;j<8;j++) acc[j] += a*bf2f(kv[j]);
  }
  float* o = ctxp + ((((size_t)sel*BB + b)*16) + s*2 + th)*1024 + g*8;
  float4 o0, o1;
  o0.x=acc[0]; o0.y=acc[1]; o0.z=acc[2]; o0.w=acc[3];
  o1.x=acc[4]; o1.y=acc[5]; o1.z=acc[6]; o1.w=acc[7];
  ((float4*)o)[0] = o0; ((float4*)o)[1] = o1;
}

// ---------------- K6: ctx reduce -> ctxe f32 (for pgen) + xb bf16 slices ----------------
__global__ __launch_bounds__(256) void k_ctxred(const float* __restrict__ ctxp,
                                                float* __restrict__ ctx_e,
                                                short* __restrict__ xb){
  int id = blockIdx.x*256 + threadIdx.x;
  int sel = id >> 16; int rem = id & 65535; int b = rem >> 10; int d = rem & 1023;
  const float* p = ctxp + (((size_t)sel*BB + b)*16)*1024 + d;
  float s = 0.f;
  #pragma unroll
  for (int i=0;i<16;i++) s += p[i*1024];
  if (sel==0) ctx_e[(size_t)b*HIDD + d] = s;
  xb[(size_t)b*3584 + 512 + sel*1024 + d] = f2bfs(s);
}

// ---------------- K7: LSTM cell (8-slot partial reduce) + bf16 h_new ----------------
__global__ __launch_bounds__(256) void k_lstm(const float* __restrict__ gp,
                                              const float* __restrict__ b_ih,
                                              const float* __restrict__ b_hh,
                                              const float* __restrict__ c_old,
                                              float* __restrict__ out,
                                              short* __restrict__ hb){
  int id = blockIdx.x*256 + threadIdx.x;    // 65536
  int b = id >> 10, j = id & 1023;
  size_t base = (size_t)b*G4;
  float gs[4];
  #pragma unroll
  for (int g=0; g<4; g++){
    int col = g*1024 + j;
    float s = b_ih[col] + b_hh[col];
    #pragma unroll
    for (int k=0;k<8;k++) s += gp[(size_t)k*(64*G4) + base + col];
    gs[g] = s;
  }
  float ig = sigmoid_f(gs[0]);
  float fg = sigmoid_f(gs[1]);
  float gg = tanhf(gs[2]);
  float og = sigmoid_f(gs[3]);
  float cn = fg*c_old[id] + ig*gg;
  float hn = og*tanhf(cn);
  out[(size_t)BB*VSZ + id] = hn;
  out[(size_t)BB*VSZ + (size_t)BB*HIDD + id] = cn;
  hb[id] = f2bfs(hn);
}

// ---------------- K8: vocab logits via MFMA, N=64/block (500 blocks, 2/CU) ----------------
__global__ __launch_bounds__(256) void k_vocab2(const short* __restrict__ hb,
                                                const float* __restrict__ Wp,
                                                const float* __restrict__ bp,
                                                float* __restrict__ out){
  int tid = threadIdx.x, l = tid & 63, w = tid >> 6;
  int l15 = l & 15, l4 = l >> 4;
  int n0 = blockIdx.x*64;          // wave w owns M-rows [w*16, w*16+16)
  f32x4 acc[4];
  #pragma unroll
  for (int j=0;j<4;j++)
    #pragma unroll
    for (int r=0;r<4;r++) acc[j][r]=0.f;
  for (int d0=0; d0<1024; d0+=32){
    bf16x8 af = *(const bf16x8*)(hb + (size_t)(w*16 + l15)*1024 + d0 + l4*8);
    bf16x8 bfr[4];
    #pragma unroll
    for (int ni=0; ni<4; ni++){
      const float* bpp = Wp + (size_t)(n0 + ni*16 + l15)*1024 + d0 + l4*8;
      float4 f0 = ((const float4*)bpp)[0], f1 = ((const float4*)bpp)[1];
      bfr[ni] = cvt8(f0, f1);
    }
    #pragma unroll
    for (int ni=0; ni<4; ni++)
      acc[ni] = __builtin_amdgcn_mfma_f32_16x16x32_bf16(af, bfr[ni], acc[ni], 0,0,0);
  }
  #pragma unroll
  for (int ni=0; ni<4; ni++)
    #pragma unroll
    for (int r=0; r<4; r++){
      int m = w*16 + l4*4 + r;
      int n = n0 + ni*16 + l15;
      out[(size_t)m*VSZ + n] = acc[ni][r] + bp[n];
    }
}

// ---------------- K9b: per-segment max + sumexp partials; seg0 also computes p_gen ----------------
__global__ __launch_bounds__(256) void k_vred(const float* __restrict__ out,
                                              const float* __restrict__ ctxe,
                                              const float* __restrict__ tab,
                                              const int* __restrict__ y,
                                              const float* __restrict__ wc,
                                              const float* __restrict__ wsv,
                                              const float* __restrict__ wy,
                                              const float* __restrict__ pgb,
                                              float* __restrict__ vm,
                                              float* __restrict__ vs,
                                              float* __restrict__ pgen_ws){
  __shared__ float red[8];
  int b = blockIdx.x, seg = blockIdx.y;
  int tid = threadIdx.x, lane = tid & 63, w = tid >> 6;
  const float* row = out + (size_t)b*VSZ;
  int lo = seg*8000, hi = lo + 8000;
  float m = -3.4e38f;
  for (int i=lo+tid; i<hi; i+=256) m = fmaxf(m, row[i]);
  m = wave_max(m);
  if (lane==0) red[w] = m;
  __syncthreads();
  m = fmaxf(fmaxf(red[0],red[1]), fmaxf(red[2],red[3]));
  float s = 0.f;
  for (int i=lo+tid; i<hi; i+=256) s += __expf(row[i]-m);
  s = wave_sum(s);
  if (lane==0) red[4+w] = s;
  __syncthreads();
  if (tid==0){
    vm[b*4+seg] = m;
    vs[b*4+seg] = red[4]+red[5]+red[6]+red[7];
  }
  if (seg==0){
    __syncthreads();
    const float* hn = out + (size_t)BB*VSZ + (size_t)b*HIDD;
    const float* emb = tab + (size_t)y[b]*EMBD;
    float acc = 0.f;
    #pragma unroll
    for (int i=0;i<4;i++){
      int d = i*256 + tid;
      acc += ctxe[(size_t)b*HIDD + d]*wc[d] + hn[d]*wsv[d];
    }
    #pragma unroll
    for (int i=0;i<2;i++){
      int d = i*256 + tid;
      acc += emb[d]*wy[d];
    }
    acc = wave_sum(acc);
    if (lane==0) red[w] = acc;
    __syncthreads();
    if (tid==0)
      pgen_ws[b] = sigmoid_f(red[0]+red[1]+red[2]+red[3] + pgb[0]);
  }
}

// ---------------- K9c: combine partials + scale pass (256 blocks) ----------------
__global__ __launch_bounds__(256) void k_vscale(float* __restrict__ out,
                                                const float* __restrict__ vm,
                                                const float* __restrict__ vs,
                                                const float* __restrict__ pgen_ws){
  int b = blockIdx.x, seg = blockIdx.y;
  int tid = threadIdx.x;
  float m0=vm[b*4+0], m1=vm[b*4+1], m2=vm[b*4+2], m3=vm[b*4+3];
  float M = fmaxf(fmaxf(m0,m1), fmaxf(m2,m3));
  float S = vs[b*4+0]*__expf(m0-M) + vs[b*4+1]*__expf(m1-M)
          + vs[b*4+2]*__expf(m2-M) + vs[b*4+3]*__expf(m3-M);
  float scale = pgen_ws[b] / S;
  float* row = out + (size_t)b*VSZ;
  int lo = seg*8000, hi = lo + 8000;
  for (int i=lo+tid; i<hi; i+=256) row[i] = __expf(row[i]-M)*scale;
}

// ---------------- K10: pointer scatter ----------------
__global__ __launch_bounds__(256) void k_scatter(const int* __restrict__ src_ids,
                                                 const float* __restrict__ att_e,
                                                 const float* __restrict__ pgen_ws,
                                                 float* __restrict__ out){
  int id = blockIdx.x*256 + threadIdx.x;
  int b = id >> 9;
  float pg = pgen_ws[b];
  int sid = src_ids[id];
  float contrib = (1.0f - pg) * att_e[id] * (sid < VSZ ? 1.0f : 0.0f);
  int safe = sid < VSZ-1 ? sid : VSZ-1;
  atomicAdd(&out[(size_t)b*VSZ + safe], contrib);
}

extern "C" void kernel_launch(void* const* d_in, const int* in_sizes, int n_in,
                              void* d_out, int out_size, void* d_ws, size_t ws_size,
                              hipStream_t stream){
  const int*   y     = (const int*)d_in[0];
  const float* h     = (const float*)d_in[1];
  const float* c     = (const float*)d_in[2];
  const float* enc   = (const float*)d_in[3];
  const float* bwd   = (const float*)d_in[4];
  const int*   sids  = (const int*)d_in[5];
  const int*   smask = (const int*)d_in[6];
  const float* tab   = (const float*)d_in[7];
  const float* W_ih  = (const float*)d_in[8];
  const float* W_hh  = (const float*)d_in[9];
  const float* b_ih  = (const float*)d_in[10];
  const float* b_hh  = (const float*)d_in[11];
  const float* Wq_e  = (const float*)d_in[12];
  const float* Wk_e  = (const float*)d_in[13];
  const float* v_e   = (const float*)d_in[14];
  const float* Wq_b  = (const float*)d_in[15];
  const float* Wk_b  = (const float*)d_in[16];
  const float* v_b   = (const float*)d_in[17];
  const float* Wp    = (const float*)d_in[18];
  const float* bp    = (const float*)d_in[19];
  const float* wc    = (const float*)d_in[20];
  const float* wsv   = (const float*)d_in[21];
  const float* wy    = (const float*)d_in[22];
  const float* pgb   = (const float*)d_in[23];
  float* out = (float*)d_out;

  float* W = (float*)d_ws;
  float* ws_qpe  = W; W += 2*BB*HIDD;        // qproj partials (2 K-split slots)
  float* ws_qpb  = W; W += 2*BB*HIDD;
  float* ws_ep   = W; W += 2*8*BB*TSEQ;      // energy partials [att][8][b][t]
  float* ws_atte = W; W += BB*TSEQ;
  float* ws_attb = W; W += BB*TSEQ;
  float* ws_ctxe = W; W += BB*HIDD;
  float* ws_ctxb = W; W += BB*HIDD;          // (unused, kept for layout stability)
  float* ws_ctxp = W; W += 2*BB*16*1024;     // 2097152 (16 slots)
  float* ws_pgen = W; W += 64;
  float* ws_vm   = W; W += 256;
  float* ws_vs   = W; W += 256;
  float* ws_gp   = W; W += 8*BB*G4;          // 2097152 (8 K-split slots)
  short* xb      = (short*)W; W += (BB*3584)/2;
  short* hb      = (short*)W; W += (BB*HIDD)/2;
  short* pk_e    = (short*)W; W += (HIDD*HIDD)/2;   // packed+swizzled Wk_e bf16
  short* pk_b    = (short*)W; W += (HIDD*HIDD)/2;
  short* pkeys   = (short*)W; W += (2*BB*TSEQ*HIDD)/2;  // 128 MB packed bf16 keys

  k_prep_all<<<33840, 256, 0, stream>>>(Wk_e, Wk_b, enc, bwd, h, tab, y,
      pk_e, pk_b, pkeys, xb);
  k_mm64<<<dim3(4,2,2), 256, 0, stream>>>(
      xb+2560, 3584, Wq_e, 1024, 1024, ws_qpe, 1024,
      xb+2560, 3584, Wq_b, 1024, 1024, ws_qpb, 1024);
  k_energy<<<4096, 256, 0, stream>>>(pkeys, pk_e, pk_b,
      ws_qpe, ws_qpb, v_e, v_b, ws_ep);
  k_softmax_t<<<dim3(BB,2), 256, 0, stream>>>(ws_ep, smask, ws_atte, ws_attb);
  k_ctx<<<dim3(BB,2,8), 256, 0, stream>>>(pkeys, ws_atte, ws_attb, ws_ctxp);
  k_ctxred<<<512, 256, 0, stream>>>(ws_ctxp, ws_ctxe, xb);
  k_mm64<<<dim3(16,4,2), 256, 0, stream>>>(
      xb,      3584, W_ih, 2560, 2560, ws_gp,             G4,
      xb+2560, 3584, W_hh, 1024, 1024, ws_gp + 4*BB*G4,   G4);
  k_lstm<<<256, 256, 0, stream>>>(ws_gp, b_ih, b_hh, c, out, hb);
  k_vocab2<<<500, 256, 0, stream>>>(hb, Wp, bp, out);
  k_vred<<<dim3(BB,4), 256, 0, stream>>>(out, ws_ctxe, tab, y, wc, wsv, wy, pgb,
      ws_vm, ws_vs, ws_pgen);
  k_vscale<<<dim3(BB,4), 256, 0, stream>>>(out, ws_vm, ws_vs, ws_pgen);
  k_scatter<<<128, 256, 0, stream>>>(sids, ws_atte, ws_pgen, out);
}

// Round 13
// 383.285 us; speedup vs baseline: 1.0575x; 1.0575x over previous
//
#include <hip/hip_runtime.h>
#include <hip/hip_bf16.h>

#define VSZ   32000
#define EMBD  512
#define HIDD  1024
#define BB    64
#define TSEQ  512
#define G4    4096

typedef short bf16x8 __attribute__((ext_vector_type(8)));
typedef float f32x4  __attribute__((ext_vector_type(4)));

typedef __attribute__((address_space(3))) unsigned       lds_u32_t;
typedef __attribute__((address_space(1))) const unsigned glb_u32_t;
__device__ __forceinline__ void gload16(const void* g, void* l){
  __builtin_amdgcn_global_load_lds((glb_u32_t*)g, (lds_u32_t*)l, 16, 0, 0);
}

__device__ __forceinline__ float sigmoid_f(float x){ return 1.0f/(1.0f+__expf(-x)); }
__device__ __forceinline__ float fast_tanh(float x){
  float e = __expf(2.0f*x);
  return 1.0f - 2.0f*__builtin_amdgcn_rcpf(e + 1.0f);
}
__device__ __forceinline__ short f2bfs(float x){
  unsigned u = __float_as_uint(x);
  unsigned r = (u + 0x7FFFu + ((u>>16)&1u)) >> 16;
  return (short)r;
}
__device__ __forceinline__ float bf2f(short s){
  return __uint_as_float(((unsigned)(unsigned short)s) << 16);
}
// single-instr packed f32x2 -> bf16x2 (RNE), gfx950
__device__ __forceinline__ unsigned cvtpk(float a, float b){
  unsigned r;
  asm("v_cvt_pk_bf16_f32 %0, %1, %2" : "=v"(r) : "v"(a), "v"(b));
  return r;
}
__device__ __forceinline__ bf16x8 cvt8(float4 a, float4 b){
  union { unsigned u[4]; bf16x8 v; } o;
  o.u[0]=cvtpk(a.x,a.y); o.u[1]=cvtpk(a.z,a.w);
  o.u[2]=cvtpk(b.x,b.y); o.u[3]=cvtpk(b.z,b.w);
  return o.v;
}
__device__ __forceinline__ float wave_sum(float x){
  #pragma unroll
  for (int off=32; off>0; off>>=1) x += __shfl_xor(x, off);
  return x;
}
__device__ __forceinline__ float wave_max(float x){
  #pragma unroll
  for (int off=32; off>0; off>>=1) x = fmaxf(x, __shfl_xor(x, off));
  return x;
}

// ---------------- merged prep: pack Wk_e/Wk_b + cvt keys + prep_h + emb gather ----------------
__global__ __launch_bounds__(256) void k_prep_all(
    const float* __restrict__ Wk_e, const float* __restrict__ Wk_b,
    const float* __restrict__ enc,  const float* __restrict__ bwd,
    const float* __restrict__ h,
    const float* __restrict__ tab,  const int* __restrict__ y,
    short* __restrict__ pk_e, short* __restrict__ pk_b,
    short* __restrict__ pkeys, short* __restrict__ xb){
  int bid = blockIdx.x;
  if (bid < 1024){
    const float* Wk = (bid < 512) ? Wk_e : Wk_b;
    short* dst      = (bid < 512) ? pk_e : pk_b;
    int id = (bid & 511)*256 + threadIdx.x;   // 131072 = 1024a * 128g
    int a = id >> 7, g = id & 127;
    int gs = (g & ~7) | ((g & 7) ^ (a & 7));
    const float* src = Wk + (size_t)a*1024 + gs*8;
    float4 f0 = ((const float4*)src)[0], f1 = ((const float4*)src)[1];
    *(bf16x8*)(dst + (size_t)id*8) = cvt8(f0, f1);
  } else if (bid < 33792){
    int r = bid - 1024;                       // 0..32767
    int att = r >> 14;
    const float* src0 = att ? bwd : enc;
    int id = (r & 16383)*256 + threadIdx.x;   // 4194304 = 32768bt * 128g
    int g = id & 127, bt = id >> 7;
    int t = bt & 511;
    int gs = (g & ~7) | ((g & 7) ^ (t & 7));
    const float* sp = src0 + (size_t)bt*1024 + gs*8;
    float4 f0 = ((const float4*)sp)[0], f1 = ((const float4*)sp)[1];
    *(bf16x8*)(pkeys + (((size_t)att*32768 + bt)*128 + g)*8) = cvt8(f0, f1);
  } else if (bid < 33824){
    int id = (bid - 33792)*256 + threadIdx.x; // 8192
    int b = id >> 7, d = (id & 127)*8;
    const float4* s = (const float4*)(h + (size_t)b*HIDD + d);
    *(bf16x8*)(xb + (size_t)b*3584 + 2560 + d) = cvt8(s[0], s[1]);
  } else {
    int id = (bid - 33824)*256 + threadIdx.x; // 4096 = 64b * 64g
    int b = id >> 6, d = (id & 63)*8;
    const float* src = tab + (size_t)y[b]*EMBD + d;
    float4 f0 = ((const float4*)src)[0], f1 = ((const float4*)src)[1];
    *(bf16x8*)(xb + (size_t)b*3584 + d) = cvt8(f0, f1);
  }
}

// ---------------- generic M=64 MFMA GEMM with K-split partials ----------------
__global__ __launch_bounds__(256) void k_mm64(
    const short* __restrict__ A0, int lda0, const float* __restrict__ B0, int ldb0, int K0, float* __restrict__ out0, int ldo0,
    const short* __restrict__ A1, int lda1, const float* __restrict__ B1, int ldb1, int K1, float* __restrict__ out1, int ldo1){
  const short* A; const float* B; float* out; int lda, ldb, K, ldo;
  if (blockIdx.z == 0){ A=A0; B=B0; out=out0; lda=lda0; ldb=ldb0; K=K0; ldo=ldo0; }
  else                { A=A1; B=B1; out=out1; lda=lda1; ldb=ldb1; K=K1; ldo=ldo1; }
  int tid = threadIdx.x, l = tid & 63, w = tid >> 6;
  int l15 = l & 15, l4 = l >> 4;
  int n0 = blockIdx.x*256 + w*64;
  int kper = K / gridDim.y;
  int dbeg = blockIdx.y * kper, dend = dbeg + kper;
  f32x4 acc[4][4];
  #pragma unroll
  for (int i=0;i<4;i++)
    #pragma unroll
    for (int j=0;j<4;j++)
      #pragma unroll
      for (int r=0;r<4;r++) acc[i][j][r]=0.f;
  for (int d0=dbeg; d0<dend; d0+=32){
    bf16x8 af[4];
    #pragma unroll
    for (int ms=0; ms<4; ms++)
      af[ms] = *(const bf16x8*)(A + (size_t)(ms*16 + l15)*lda + d0 + l4*8);
    bf16x8 bfr[4];
    #pragma unroll
    for (int ni=0; ni<4; ni++){
      const float* bp = B + (size_t)(n0 + ni*16 + l15)*ldb + d0 + l4*8;
      float4 f0 = ((const float4*)bp)[0], f1 = ((const float4*)bp)[1];
      bfr[ni] = cvt8(f0, f1);
    }
    #pragma unroll
    for (int ms=0; ms<4; ms++)
      #pragma unroll
      for (int ni=0; ni<4; ni++)
        acc[ms][ni] = __builtin_amdgcn_mfma_f32_16x16x32_bf16(af[ms], bfr[ni], acc[ms][ni], 0,0,0);
  }
  float* op = out + (size_t)blockIdx.y * 64 * ldo;
  #pragma unroll
  for (int ms=0; ms<4; ms++)
    #pragma unroll
    for (int ni=0; ni<4; ni++)
      #pragma unroll
      for (int r=0; r<4; r++){
        int m = ms*16 + l4*4 + r;
        op[(size_t)m*ldo + n0 + ni*16 + l15] = acc[ms][ni][r];
      }
}

// ---------------- K3: energy 128x128x1024 GEMM, BOTH operands via global_load_lds ----------------
// (unchanged: 173 us, MfmaUtil 35%, conflicts 0 — m97-structure ceiling)
__global__ __launch_bounds__(256,3) void k_energy(
    const short* __restrict__ pkeys,
    const short* __restrict__ pke, const short* __restrict__ pkb,
    const float* __restrict__ qpe, const float* __restrict__ qpb,
    const float* __restrict__ ve, const float* __restrict__ vb,
    float* __restrict__ ep_out){                                   // [att][8][64][512]
  __shared__ short A_s[128*64];
  __shared__ short B_s[128*64];
  __shared__ float ebuf[2][128];

  int wg = blockIdx.x;
  int xcd = wg & 7, idx = wg >> 3;
  int tglob = xcd*64 + (idx >> 3);
  int A0 = idx & 7;
  int att = tglob >> 8;
  int tt  = tglob & 255;
  int b = tt >> 2, t0 = (tt & 3)*128;

  const short* pk = att ? pkb : pke;
  const float* qp = att ? qpb : qpe;
  const float* v  = att ? vb  : ve;

  int tid = threadIdx.x, l = tid & 63, w = tid >> 6;
  int l15 = l & 15, l4 = l >> 4;
  int wr = w >> 1, wc = w & 1;

  const char* asrc = (const char*)(pkeys + ((size_t)att*32768 + (size_t)b*512)*1024)
                   + (size_t)(t0 + w*32 + (l>>3))*2048 + (l&7)*16;
  const char* bsrc = (const char*)pk + (size_t)(A0*128 + w*32 + (l>>3))*2048 + (l&7)*16;

  f32x4 acc[4][4];
  #pragma unroll
  for (int i=0;i<4;i++)
    #pragma unroll
    for (int j=0;j<4;j++)
      #pragma unroll
      for (int r=0;r<4;r++) acc[i][j][r]=0.f;

  for (int c=0; c<16; ++c){
    if (c) __syncthreads();
    #pragma unroll
    for (int k=0;k<4;k++)
      gload16(asrc + (size_t)c*128 + (size_t)k*16384, (char*)A_s + w*4096 + k*1024);
    #pragma unroll
    for (int k=0;k<4;k++)
      gload16(bsrc + (size_t)c*128 + (size_t)k*16384, (char*)B_s + w*4096 + k*1024);
    __syncthreads();
    #pragma unroll
    for (int ks=0; ks<2; ks++){
      bf16x8 af[4], bf[4];
      #pragma unroll
      for (int ms=0; ms<4; ms++){
        int row = wr*64 + ms*16 + l15;
        af[ms] = *(const bf16x8*)((char*)A_s + row*128 + ((ks*64 + l4*16) ^ ((row&7)<<4)));
      }
      #pragma unroll
      for (int ni=0; ni<4; ni++){
        int row = wc*64 + ni*16 + l15;
        bf[ni] = *(const bf16x8*)((char*)B_s + row*128 + ((ks*64 + l4*16) ^ ((row&7)<<4)));
      }
      #pragma unroll
      for (int ms=0; ms<4; ms++)
        #pragma unroll
        for (int ni=0; ni<4; ni++)
          acc[ms][ni] = __builtin_amdgcn_mfma_f32_16x16x32_bf16(af[ms], bf[ni], acc[ms][ni], 0,0,0);
    }
  }

  float qv[4], vv[4];
  #pragma unroll
  for (int ni=0; ni<4; ni++){
    int a = A0*128 + wc*64 + ni*16 + l15;
    qv[ni] = qp[(size_t)b*HIDD + a] + qp[65536 + (size_t)b*HIDD + a];
    vv[ni] = v[a];
  }
  float es[16];
  #pragma unroll
  for (int ms=0; ms<4; ms++)
    #pragma unroll
    for (int r=0; r<4; r++){
      float s = 0.f;
      #pragma unroll
      for (int ni=0; ni<4; ni++)
        s += vv[ni]*fast_tanh(qv[ni] + acc[ms][ni][r]);
      es[ms*4+r] = s;
    }
  #pragma unroll
  for (int i=0;i<16;i++){
    float x = es[i];
    x += __shfl_xor(x,1); x += __shfl_xor(x,2);
    x += __shfl_xor(x,4); x += __shfl_xor(x,8);
    es[i] = x;
  }
  if (l15 == 0){
    #pragma unroll
    for (int ms=0; ms<4; ms++)
      #pragma unroll
      for (int r=0; r<4; r++)
        ebuf[wc][wr*64 + ms*16 + l4*4 + r] = es[ms*4+r];
  }
  __syncthreads();
  if (tid < 128)
    ep_out[(((size_t)att*8 + A0)*BB + b)*TSEQ + t0 + tid] = ebuf[0][tid] + ebuf[1][tid];
}

// ---------------- K4: softmax over T (sums 8 a-tile partials, applies mask) ----------------
__global__ __launch_bounds__(256) void k_softmax_t(const float* __restrict__ ep,
                                                   const int* __restrict__ mask,
                                                   float* __restrict__ att_e,
                                                   float* __restrict__ att_b){
  int b = blockIdx.x, att = blockIdx.y;
  float* e = (att ? att_b : att_e) + (size_t)b*TSEQ;
  __shared__ float red[8];
  int tid = threadIdx.x, lane = tid & 63, w = tid >> 6;
  float v0 = 0.f, v1 = 0.f;
  #pragma unroll
  for (int i=0;i<8;i++){
    const float* p = ep + (((size_t)att*8 + i)*BB + b)*TSEQ;
    v0 += p[tid]; v1 += p[tid+256];
  }
  if (att==0){
    if (mask[(size_t)b*TSEQ + tid]==0)      v0 = -3.4e38f;
    if (mask[(size_t)b*TSEQ + tid+256]==0)  v1 = -3.4e38f;
  }
  float m = wave_max(fmaxf(v0, v1));
  if (lane==0) red[w] = m;
  __syncthreads();
  m = fmaxf(fmaxf(red[0],red[1]), fmaxf(red[2],red[3]));
  float x0 = __expf(v0-m), x1 = __expf(v1-m);
  float s = wave_sum(x0+x1);
  if (lane==0) red[4+w] = s;
  __syncthreads();
  s = red[4]+red[5]+red[6]+red[7];
  float inv = 1.0f/s;
  e[tid] = x0*inv; e[tid+256] = x1*inv;
}

// ---------------- K5: context = attn @ keys, reading packed bf16 keys ----------------
__global__ __launch_bounds__(256) void k_ctx(const short* __restrict__ pkeys,
                                             const float* __restrict__ att_e,
                                             const float* __restrict__ att_b,
                                             float* __restrict__ ctxp){
  int b = blockIdx.x, sel = blockIdx.y, s = blockIdx.z;
  const short* base = pkeys + (((size_t)sel*32768) + (size_t)b*512 + s*64)*1024;
  const float* att  = (sel ? att_b : att_e) + (size_t)b*TSEQ + s*64;
  int g = threadIdx.x & 127, th = threadIdx.x >> 7;
  const short* rp = base + (size_t)th*32*1024;
  float acc[8];
  #pragma unroll
  for (int j=0;j<8;j++) acc[j]=0.f;
  for (int t=0;t<32;t++){
    float a = att[th*32 + t];
    int gg = (g & ~7) | ((g & 7) ^ (t & 7));
    bf16x8 kv = *(const bf16x8*)(rp + (size_t)t*1024 + gg*8);
    #pragma unroll
    for (int j=0;j<8;j++) acc[j] += a*bf2f(kv[j]);
  }
  float* o = ctxp + ((((size_t)sel*BB + b)*16) + s*2 + th)*1024 + g*8;
  float4 o0, o1;
  o0.x=acc[0]; o0.y=acc[1]; o0.z=acc[2]; o0.w=acc[3];
  o1.x=acc[4]; o1.y=acc[5]; o1.z=acc[6]; o1.w=acc[7];
  ((float4*)o)[0] = o0; ((float4*)o)[1] = o1;
}

// ---------------- K6: ctx reduce -> ctxe f32 (for pgen) + xb bf16 slices ----------------
__global__ __launch_bounds__(256) void k_ctxred(const float* __restrict__ ctxp,
                                                float* __restrict__ ctx_e,
                                                short* __restrict__ xb){
  int id = blockIdx.x*256 + threadIdx.x;
  int sel = id >> 16; int rem = id & 65535; int b = rem >> 10; int d = rem & 1023;
  const float* p = ctxp + (((size_t)sel*BB + b)*16)*1024 + d;
  float s = 0.f;
  #pragma unroll
  for (int i=0;i<16;i++) s += p[i*1024];
  if (sel==0) ctx_e[(size_t)b*HIDD + d] = s;
  xb[(size_t)b*3584 + 512 + sel*1024 + d] = f2bfs(s);
}

// ---------------- K7: LSTM cell (8-slot partial reduce) + bf16 h_new ----------------
__global__ __launch_bounds__(256) void k_lstm(const float* __restrict__ gp,
                                              const float* __restrict__ b_ih,
                                              const float* __restrict__ b_hh,
                                              const float* __restrict__ c_old,
                                              float* __restrict__ out,
                                              short* __restrict__ hb){
  int id = blockIdx.x*256 + threadIdx.x;    // 65536
  int b = id >> 10, j = id & 1023;
  size_t base = (size_t)b*G4;
  float gs[4];
  #pragma unroll
  for (int g=0; g<4; g++){
    int col = g*1024 + j;
    float s = b_ih[col] + b_hh[col];
    #pragma unroll
    for (int k=0;k<8;k++) s += gp[(size_t)k*(64*G4) + base + col];
    gs[g] = s;
  }
  float ig = sigmoid_f(gs[0]);
  float fg = sigmoid_f(gs[1]);
  float gg = tanhf(gs[2]);
  float og = sigmoid_f(gs[3]);
  float cn = fg*c_old[id] + ig*gg;
  float hn = og*tanhf(cn);
  out[(size_t)BB*VSZ + id] = hn;
  out[(size_t)BB*VSZ + (size_t)BB*HIDD + id] = cn;
  hb[id] = f2bfs(hn);
}

// ---------------- K8: vocab logits via MFMA, N=128/block (250 blocks) ----------------
__global__ __launch_bounds__(256) void k_vocab2(const short* __restrict__ hb,
                                                const float* __restrict__ Wp,
                                                const float* __restrict__ bp,
                                                float* __restrict__ out){
  int tid = threadIdx.x, l = tid & 63, w = tid >> 6;
  int l15 = l & 15, l4 = l >> 4;
  int mh = w >> 1;
  int n0 = blockIdx.x*128 + (w&1)*64;
  f32x4 acc[2][4];
  #pragma unroll
  for (int i=0;i<2;i++)
    #pragma unroll
    for (int j=0;j<4;j++)
      #pragma unroll
      for (int r=0;r<4;r++) acc[i][j][r]=0.f;
  for (int d0=0; d0<1024; d0+=32){
    bf16x8 af[2];
    #pragma unroll
    for (int ms=0; ms<2; ms++)
      af[ms] = *(const bf16x8*)(hb + (size_t)(mh*32 + ms*16 + l15)*1024 + d0 + l4*8);
    bf16x8 bfr[4];
    #pragma unroll
    for (int ni=0; ni<4; ni++){
      const float* bpp = Wp + (size_t)(n0 + ni*16 + l15)*1024 + d0 + l4*8;
      float4 f0 = ((const float4*)bpp)[0], f1 = ((const float4*)bpp)[1];
      bfr[ni] = cvt8(f0, f1);
    }
    #pragma unroll
    for (int ms=0; ms<2; ms++)
      #pragma unroll
      for (int ni=0; ni<4; ni++)
        acc[ms][ni] = __builtin_amdgcn_mfma_f32_16x16x32_bf16(af[ms], bfr[ni], acc[ms][ni], 0,0,0);
  }
  #pragma unroll
  for (int ms=0; ms<2; ms++)
    #pragma unroll
    for (int ni=0; ni<4; ni++)
      #pragma unroll
      for (int r=0; r<4; r++){
        int m = mh*32 + ms*16 + l4*4 + r;
        int n = n0 + ni*16 + l15;
        out[(size_t)m*VSZ + n] = acc[ms][ni][r] + bp[n];
      }
}

// ---------------- K9a: p_gen (64 blocks) ----------------
__global__ __launch_bounds__(256) void k_pgen(const float* __restrict__ ctxe,
                                              const float* __restrict__ tab,
                                              const int* __restrict__ y,
                                              const float* __restrict__ wc,
                                              const float* __restrict__ wsv,
                                              const float* __restrict__ wy,
                                              const float* __restrict__ pgb,
                                              const float* __restrict__ out,
                                              float* __restrict__ pgen_ws){
  __shared__ float red[4];
  int b = blockIdx.x, tid = threadIdx.x, lane = tid & 63, w = tid >> 6;
  const float* hn = out + (size_t)BB*VSZ + (size_t)b*HIDD;
  const float* emb = tab + (size_t)y[b]*EMBD;
  float acc = 0.f;
  #pragma unroll
  for (int i=0;i<4;i++){
    int d = i*256 + tid;
    acc += ctxe[(size_t)b*HIDD + d]*wc[d] + hn[d]*wsv[d];
  }
  #pragma unroll
  for (int i=0;i<2;i++){
    int d = i*256 + tid;
    acc += emb[d]*wy[d];
  }
  acc = wave_sum(acc);
  if (lane==0) red[w] = acc;
  __syncthreads();
  if (tid==0)
    pgen_ws[b] = sigmoid_f(red[0]+red[1]+red[2]+red[3] + pgb[0]);
}

// ---------------- K9b: per-segment max + sumexp partials (256 blocks) ----------------
__global__ __launch_bounds__(256) void k_vred(const float* __restrict__ out,
                                              float* __restrict__ vm,
                                              float* __restrict__ vs){
  __shared__ float red[8];
  int b = blockIdx.x, seg = blockIdx.y;
  int tid = threadIdx.x, lane = tid & 63, w = tid >> 6;
  const float* row = out + (size_t)b*VSZ;
  int lo = seg*8000, hi = lo + 8000;
  float m = -3.4e38f;
  for (int i=lo+tid; i<hi; i+=256) m = fmaxf(m, row[i]);
  m = wave_max(m);
  if (lane==0) red[w] = m;
  __syncthreads();
  m = fmaxf(fmaxf(red[0],red[1]), fmaxf(red[2],red[3]));
  float s = 0.f;
  for (int i=lo+tid; i<hi; i+=256) s += __expf(row[i]-m);
  s = wave_sum(s);
  if (lane==0) red[4+w] = s;
  __syncthreads();
  if (tid==0){
    vm[b*4+seg] = m;
    vs[b*4+seg] = red[4]+red[5]+red[6]+red[7];
  }
}

// ---------------- K9c: combine partials + scale pass (256 blocks) ----------------
__global__ __launch_bounds__(256) void k_vscale(float* __restrict__ out,
                                                const float* __restrict__ vm,
                                                const float* __restrict__ vs,
                                                const float* __restrict__ pgen_ws){
  int b = blockIdx.x, seg = blockIdx.y;
  int tid = threadIdx.x;
  float m0=vm[b*4+0], m1=vm[b*4+1], m2=vm[b*4+2], m3=vm[b*4+3];
  float M = fmaxf(fmaxf(m0,m1), fmaxf(m2,m3));
  float S = vs[b*4+0]*__expf(m0-M) + vs[b*4+1]*__expf(m1-M)
          + vs[b*4+2]*__expf(m2-M) + vs[b*4+3]*__expf(m3-M);
  float scale = pgen_ws[b] / S;
  float* row = out + (size_t)b*VSZ;
  int lo = seg*8000, hi = lo + 8000;
  for (int i=lo+tid; i<hi; i+=256) row[i] = __expf(row[i]-M)*scale;
}

// ---------------- K10: pointer scatter ----------------
__global__ __launch_bounds__(256) void k_scatter(const int* __restrict__ src_ids,
                                                 const float* __restrict__ att_e,
                                                 const float* __restrict__ pgen_ws,
                                                 float* __restrict__ out){
  int id = blockIdx.x*256 + threadIdx.x;
  int b = id >> 9;
  float pg = pgen_ws[b];
  int sid = src_ids[id];
  float contrib = (1.0f - pg) * att_e[id] * (sid < VSZ ? 1.0f : 0.0f);
  int safe = sid < VSZ-1 ? sid : VSZ-1;
  atomicAdd(&out[(size_t)b*VSZ + safe], contrib);
}

extern "C" void kernel_launch(void* const* d_in, const int* in_sizes, int n_in,
                              void* d_out, int out_size, void* d_ws, size_t ws_size,
                              hipStream_t stream){
  const int*   y     = (const int*)d_in[0];
  const float* h     = (const float*)d_in[1];
  const float* c     = (const float*)d_in[2];
  const float* enc   = (const float*)d_in[3];
  const float* bwd   = (const float*)d_in[4];
  const int*   sids  = (const int*)d_in[5];
  const int*   smask = (const int*)d_in[6];
  const float* tab   = (const float*)d_in[7];
  const float* W_ih  = (const float*)d_in[8];
  const float* W_hh  = (const float*)d_in[9];
  const float* b_ih  = (const float*)d_in[10];
  const float* b_hh  = (const float*)d_in[11];
  const float* Wq_e  = (const float*)d_in[12];
  const float* Wk_e  = (const float*)d_in[13];
  const float* v_e   = (const float*)d_in[14];
  const float* Wq_b  = (const float*)d_in[15];
  const float* Wk_b  = (const float*)d_in[16];
  const float* v_b   = (const float*)d_in[17];
  const float* Wp    = (const float*)d_in[18];
  const float* bp    = (const float*)d_in[19];
  const float* wc    = (const float*)d_in[20];
  const float* wsv   = (const float*)d_in[21];
  const float* wy    = (const float*)d_in[22];
  const float* pgb   = (const float*)d_in[23];
  float* out = (float*)d_out;

  float* W = (float*)d_ws;
  float* ws_qpe  = W; W += 2*BB*HIDD;        // qproj partials (2 K-split slots)
  float* ws_qpb  = W; W += 2*BB*HIDD;
  float* ws_ep   = W; W += 2*8*BB*TSEQ;      // energy partials [att][8][b][t]
  float* ws_atte = W; W += BB*TSEQ;
  float* ws_attb = W; W += BB*TSEQ;
  float* ws_ctxe = W; W += BB*HIDD;
  float* ws_ctxb = W; W += BB*HIDD;          // (unused, layout stability)
  float* ws_ctxp = W; W += 2*BB*16*1024;     // 2097152 (16 slots)
  float* ws_pgen = W; W += 64;
  float* ws_vm   = W; W += 256;
  float* ws_vs   = W; W += 256;
  float* ws_gp   = W; W += 8*BB*G4;          // 2097152 (8 K-split slots)
  short* xb      = (short*)W; W += (BB*3584)/2;
  short* hb      = (short*)W; W += (BB*HIDD)/2;
  short* pk_e    = (short*)W; W += (HIDD*HIDD)/2;   // packed+swizzled Wk_e bf16
  short* pk_b    = (short*)W; W += (HIDD*HIDD)/2;
  short* pkeys   = (short*)W; W += (2*BB*TSEQ*HIDD)/2;  // 128 MB packed bf16 keys

  k_prep_all<<<33840, 256, 0, stream>>>(Wk_e, Wk_b, enc, bwd, h, tab, y,
      pk_e, pk_b, pkeys, xb);
  k_mm64<<<dim3(4,2,2), 256, 0, stream>>>(
      xb+2560, 3584, Wq_e, 1024, 1024, ws_qpe, 1024,
      xb+2560, 3584, Wq_b, 1024, 1024, ws_qpb, 1024);
  k_energy<<<4096, 256, 0, stream>>>(pkeys, pk_e, pk_b,
      ws_qpe, ws_qpb, v_e, v_b, ws_ep);
  k_softmax_t<<<dim3(BB,2), 256, 0, stream>>>(ws_ep, smask, ws_atte, ws_attb);
  k_ctx<<<dim3(BB,2,8), 256, 0, stream>>>(pkeys, ws_atte, ws_attb, ws_ctxp);
  k_ctxred<<<512, 256, 0, stream>>>(ws_ctxp, ws_ctxe, xb);
  k_mm64<<<dim3(16,4,2), 256, 0, stream>>>(
      xb,      3584, W_ih, 2560, 2560, ws_gp,             G4,
      xb+2560, 3584, W_hh, 1024, 1024, ws_gp + 4*BB*G4,   G4);
  k_lstm<<<256, 256, 0, stream>>>(ws_gp, b_ih, b_hh, c, out, hb);
  k_vocab2<<<250, 256, 0, stream>>>(hb, Wp, bp, out);
  k_pgen<<<BB, 256, 0, stream>>>(ws_ctxe, tab, y, wc, wsv, wy, pgb, out, ws_pgen);
  k_vred<<<dim3(BB,4), 256, 0, stream>>>(out, ws_vm, ws_vs);
  k_vscale<<<dim3(BB,4), 256, 0, stream>>>(out, ws_vm, ws_vs, ws_pgen);
  k_scatter<<<128, 256, 0, stream>>>(sids, ws_atte, ws_pgen, out);
}

// Round 14
// 366.849 us; speedup vs baseline: 1.1049x; 1.0448x over previous
//
#include <hip/hip_runtime.h>
#include <hip/hip_bf16.h>

#define VSZ   32000
#define EMBD  512
#define HIDD  1024
#define BB    64
#define TSEQ  512
#define G4    4096

typedef short bf16x8 __attribute__((ext_vector_type(8)));
typedef float f32x4  __attribute__((ext_vector_type(4)));

typedef __attribute__((address_space(3))) unsigned       lds_u32_t;
typedef __attribute__((address_space(1))) const unsigned glb_u32_t;
__device__ __forceinline__ void gload16(const void* g, void* l){
  __builtin_amdgcn_global_load_lds((glb_u32_t*)g, (lds_u32_t*)l, 16, 0, 0);
}

__device__ __forceinline__ float sigmoid_f(float x){ return 1.0f/(1.0f+__expf(-x)); }
__device__ __forceinline__ float fast_tanh(float x){
  float e = __expf(2.0f*x);
  return 1.0f - 2.0f*__builtin_amdgcn_rcpf(e + 1.0f);
}
__device__ __forceinline__ short f2bfs(float x){
  unsigned u = __float_as_uint(x);
  unsigned r = (u + 0x7FFFu + ((u>>16)&1u)) >> 16;
  return (short)r;
}
__device__ __forceinline__ float bf2f(short s){
  return __uint_as_float(((unsigned)(unsigned short)s) << 16);
}
// single-instr packed f32x2 -> bf16x2 (RNE), gfx950
__device__ __forceinline__ unsigned cvtpk(float a, float b){
  unsigned r;
  asm("v_cvt_pk_bf16_f32 %0, %1, %2" : "=v"(r) : "v"(a), "v"(b));
  return r;
}
__device__ __forceinline__ bf16x8 cvt8(float4 a, float4 b){
  union { unsigned u[4]; bf16x8 v; } o;
  o.u[0]=cvtpk(a.x,a.y); o.u[1]=cvtpk(a.z,a.w);
  o.u[2]=cvtpk(b.x,b.y); o.u[3]=cvtpk(b.z,b.w);
  return o.v;
}
__device__ __forceinline__ float wave_sum(float x){
  #pragma unroll
  for (int off=32; off>0; off>>=1) x += __shfl_xor(x, off);
  return x;
}
__device__ __forceinline__ float wave_max(float x){
  #pragma unroll
  for (int off=32; off>0; off>>=1) x = fmaxf(x, __shfl_xor(x, off));
  return x;
}

// ---------------- merged prep: pack Wk_e/Wk_b + cvt keys + prep_h + emb gather ----------------
__global__ __launch_bounds__(256) void k_prep_all(
    const float* __restrict__ Wk_e, const float* __restrict__ Wk_b,
    const float* __restrict__ enc,  const float* __restrict__ bwd,
    const float* __restrict__ h,
    const float* __restrict__ tab,  const int* __restrict__ y,
    short* __restrict__ pk_e, short* __restrict__ pk_b,
    short* __restrict__ pkeys, short* __restrict__ xb){
  int bid = blockIdx.x;
  if (bid < 1024){
    const float* Wk = (bid < 512) ? Wk_e : Wk_b;
    short* dst      = (bid < 512) ? pk_e : pk_b;
    int id = (bid & 511)*256 + threadIdx.x;   // 131072 = 1024a * 128g
    int a = id >> 7, g = id & 127;
    int gs = (g & ~7) | ((g & 7) ^ (a & 7));
    const float* src = Wk + (size_t)a*1024 + gs*8;
    float4 f0 = ((const float4*)src)[0], f1 = ((const float4*)src)[1];
    *(bf16x8*)(dst + (size_t)id*8) = cvt8(f0, f1);
  } else if (bid < 33792){
    int r = bid - 1024;                       // 0..32767
    int att = r >> 14;
    const float* src0 = att ? bwd : enc;
    int id = (r & 16383)*256 + threadIdx.x;   // 4194304 = 32768bt * 128g
    int g = id & 127, bt = id >> 7;
    int t = bt & 511;
    int gs = (g & ~7) | ((g & 7) ^ (t & 7));
    const float* sp = src0 + (size_t)bt*1024 + gs*8;
    float4 f0 = ((const float4*)sp)[0], f1 = ((const float4*)sp)[1];
    *(bf16x8*)(pkeys + (((size_t)att*32768 + bt)*128 + g)*8) = cvt8(f0, f1);
  } else if (bid < 33824){
    int id = (bid - 33792)*256 + threadIdx.x; // 8192
    int b = id >> 7, d = (id & 127)*8;
    const float4* s = (const float4*)(h + (size_t)b*HIDD + d);
    *(bf16x8*)(xb + (size_t)b*3584 + 2560 + d) = cvt8(s[0], s[1]);
  } else {
    int id = (bid - 33824)*256 + threadIdx.x; // 4096 = 64b * 64g
    int b = id >> 6, d = (id & 63)*8;
    const float* src = tab + (size_t)y[b]*EMBD + d;
    float4 f0 = ((const float4*)src)[0], f1 = ((const float4*)src)[1];
    *(bf16x8*)(xb + (size_t)b*3584 + d) = cvt8(f0, f1);
  }
}

// ---------------- generic M=64 MFMA GEMM with K-split partials ----------------
__global__ __launch_bounds__(256) void k_mm64(
    const short* __restrict__ A0, int lda0, const float* __restrict__ B0, int ldb0, int K0, float* __restrict__ out0, int ldo0,
    const short* __restrict__ A1, int lda1, const float* __restrict__ B1, int ldb1, int K1, float* __restrict__ out1, int ldo1){
  const short* A; const float* B; float* out; int lda, ldb, K, ldo;
  if (blockIdx.z == 0){ A=A0; B=B0; out=out0; lda=lda0; ldb=ldb0; K=K0; ldo=ldo0; }
  else                { A=A1; B=B1; out=out1; lda=lda1; ldb=ldb1; K=K1; ldo=ldo1; }
  int tid = threadIdx.x, l = tid & 63, w = tid >> 6;
  int l15 = l & 15, l4 = l >> 4;
  int n0 = blockIdx.x*256 + w*64;
  int kper = K / gridDim.y;
  int dbeg = blockIdx.y * kper, dend = dbeg + kper;
  f32x4 acc[4][4];
  #pragma unroll
  for (int i=0;i<4;i++)
    #pragma unroll
    for (int j=0;j<4;j++)
      #pragma unroll
      for (int r=0;r<4;r++) acc[i][j][r]=0.f;
  for (int d0=dbeg; d0<dend; d0+=32){
    bf16x8 af[4];
    #pragma unroll
    for (int ms=0; ms<4; ms++)
      af[ms] = *(const bf16x8*)(A + (size_t)(ms*16 + l15)*lda + d0 + l4*8);
    bf16x8 bfr[4];
    #pragma unroll
    for (int ni=0; ni<4; ni++){
      const float* bp = B + (size_t)(n0 + ni*16 + l15)*ldb + d0 + l4*8;
      float4 f0 = ((const float4*)bp)[0], f1 = ((const float4*)bp)[1];
      bfr[ni] = cvt8(f0, f1);
    }
    #pragma unroll
    for (int ms=0; ms<4; ms++)
      #pragma unroll
      for (int ni=0; ni<4; ni++)
        acc[ms][ni] = __builtin_amdgcn_mfma_f32_16x16x32_bf16(af[ms], bfr[ni], acc[ms][ni], 0,0,0);
  }
  float* op = out + (size_t)blockIdx.y * 64 * ldo;
  #pragma unroll
  for (int ms=0; ms<4; ms++)
    #pragma unroll
    for (int ni=0; ni<4; ni++)
      #pragma unroll
      for (int r=0; r<4; r++){
        int m = ms*16 + l4*4 + r;
        op[(size_t)m*ldo + n0 + ni*16 + l15] = acc[ms][ni][r];
      }
}

// ---------------- K3: energy 128x128x1024 GEMM, BOTH operands via global_load_lds ----------------
// (unchanged structure: 173 us, MfmaUtil 35%, conflicts 0 — m97-structure ceiling;
//  epilogue now sums 8 qproj K-split partials)
__global__ __launch_bounds__(256,3) void k_energy(
    const short* __restrict__ pkeys,
    const short* __restrict__ pke, const short* __restrict__ pkb,
    const float* __restrict__ qpe, const float* __restrict__ qpb,  // [8][64][1024] partials
    const float* __restrict__ ve, const float* __restrict__ vb,
    float* __restrict__ ep_out){                                   // [att][8][64][512]
  __shared__ short A_s[128*64];
  __shared__ short B_s[128*64];
  __shared__ float ebuf[2][128];

  int wg = blockIdx.x;
  int xcd = wg & 7, idx = wg >> 3;
  int tglob = xcd*64 + (idx >> 3);
  int A0 = idx & 7;
  int att = tglob >> 8;
  int tt  = tglob & 255;
  int b = tt >> 2, t0 = (tt & 3)*128;

  const short* pk = att ? pkb : pke;
  const float* qp = att ? qpb : qpe;
  const float* v  = att ? vb  : ve;

  int tid = threadIdx.x, l = tid & 63, w = tid >> 6;
  int l15 = l & 15, l4 = l >> 4;
  int wr = w >> 1, wc = w & 1;

  const char* asrc = (const char*)(pkeys + ((size_t)att*32768 + (size_t)b*512)*1024)
                   + (size_t)(t0 + w*32 + (l>>3))*2048 + (l&7)*16;
  const char* bsrc = (const char*)pk + (size_t)(A0*128 + w*32 + (l>>3))*2048 + (l&7)*16;

  f32x4 acc[4][4];
  #pragma unroll
  for (int i=0;i<4;i++)
    #pragma unroll
    for (int j=0;j<4;j++)
      #pragma unroll
      for (int r=0;r<4;r++) acc[i][j][r]=0.f;

  for (int c=0; c<16; ++c){
    if (c) __syncthreads();
    #pragma unroll
    for (int k=0;k<4;k++)
      gload16(asrc + (size_t)c*128 + (size_t)k*16384, (char*)A_s + w*4096 + k*1024);
    #pragma unroll
    for (int k=0;k<4;k++)
      gload16(bsrc + (size_t)c*128 + (size_t)k*16384, (char*)B_s + w*4096 + k*1024);
    __syncthreads();
    #pragma unroll
    for (int ks=0; ks<2; ks++){
      bf16x8 af[4], bf[4];
      #pragma unroll
      for (int ms=0; ms<4; ms++){
        int row = wr*64 + ms*16 + l15;
        af[ms] = *(const bf16x8*)((char*)A_s + row*128 + ((ks*64 + l4*16) ^ ((row&7)<<4)));
      }
      #pragma unroll
      for (int ni=0; ni<4; ni++){
        int row = wc*64 + ni*16 + l15;
        bf[ni] = *(const bf16x8*)((char*)B_s + row*128 + ((ks*64 + l4*16) ^ ((row&7)<<4)));
      }
      #pragma unroll
      for (int ms=0; ms<4; ms++)
        #pragma unroll
        for (int ni=0; ni<4; ni++)
          acc[ms][ni] = __builtin_amdgcn_mfma_f32_16x16x32_bf16(af[ms], bf[ni], acc[ms][ni], 0,0,0);
    }
  }

  float qv[4], vv[4];
  #pragma unroll
  for (int ni=0; ni<4; ni++){
    int a = A0*128 + wc*64 + ni*16 + l15;
    float q = 0.f;
    #pragma unroll
    for (int s=0; s<8; s++) q += qp[(size_t)s*65536 + (size_t)b*HIDD + a];
    qv[ni] = q;
    vv[ni] = v[a];
  }
  float es[16];
  #pragma unroll
  for (int ms=0; ms<4; ms++)
    #pragma unroll
    for (int r=0; r<4; r++){
      float s = 0.f;
      #pragma unroll
      for (int ni=0; ni<4; ni++)
        s += vv[ni]*fast_tanh(qv[ni] + acc[ms][ni][r]);
      es[ms*4+r] = s;
    }
  #pragma unroll
  for (int i=0;i<16;i++){
    float x = es[i];
    x += __shfl_xor(x,1); x += __shfl_xor(x,2);
    x += __shfl_xor(x,4); x += __shfl_xor(x,8);
    es[i] = x;
  }
  if (l15 == 0){
    #pragma unroll
    for (int ms=0; ms<4; ms++)
      #pragma unroll
      for (int r=0; r<4; r++)
        ebuf[wc][wr*64 + ms*16 + l4*4 + r] = es[ms*4+r];
  }
  __syncthreads();
  if (tid < 128)
    ep_out[(((size_t)att*8 + A0)*BB + b)*TSEQ + t0 + tid] = ebuf[0][tid] + ebuf[1][tid];
}

// ---------------- K4: softmax over T (sums 8 a-tile partials, applies mask) ----------------
__global__ __launch_bounds__(256) void k_softmax_t(const float* __restrict__ ep,
                                                   const int* __restrict__ mask,
                                                   float* __restrict__ att_e,
                                                   float* __restrict__ att_b){
  int b = blockIdx.x, att = blockIdx.y;
  float* e = (att ? att_b : att_e) + (size_t)b*TSEQ;
  __shared__ float red[8];
  int tid = threadIdx.x, lane = tid & 63, w = tid >> 6;
  float v0 = 0.f, v1 = 0.f;
  #pragma unroll
  for (int i=0;i<8;i++){
    const float* p = ep + (((size_t)att*8 + i)*BB + b)*TSEQ;
    v0 += p[tid]; v1 += p[tid+256];
  }
  if (att==0){
    if (mask[(size_t)b*TSEQ + tid]==0)      v0 = -3.4e38f;
    if (mask[(size_t)b*TSEQ + tid+256]==0)  v1 = -3.4e38f;
  }
  float m = wave_max(fmaxf(v0, v1));
  if (lane==0) red[w] = m;
  __syncthreads();
  m = fmaxf(fmaxf(red[0],red[1]), fmaxf(red[2],red[3]));
  float x0 = __expf(v0-m), x1 = __expf(v1-m);
  float s = wave_sum(x0+x1);
  if (lane==0) red[4+w] = s;
  __syncthreads();
  s = red[4]+red[5]+red[6]+red[7];
  float inv = 1.0f/s;
  e[tid] = x0*inv; e[tid+256] = x1*inv;
}

// ---------------- K5: context = attn @ keys, reading packed bf16 keys ----------------
__global__ __launch_bounds__(256) void k_ctx(const short* __restrict__ pkeys,
                                             const float* __restrict__ att_e,
                                             const float* __restrict__ att_b,
                                             float* __restrict__ ctxp){
  int b = blockIdx.x, sel = blockIdx.y, s = blockIdx.z;
  const short* base = pkeys + (((size_t)sel*32768) + (size_t)b*512 + s*64)*1024;
  const float* att  = (sel ? att_b : att_e) + (size_t)b*TSEQ + s*64;
  int g = threadIdx.x & 127, th = threadIdx.x >> 7;
  const short* rp = base + (size_t)th*32*1024;
  float acc[8];
  #pragma unroll
  for (int j=0;j<8;j++) acc[j]=0.f;
  for (int t=0;t<32;t++){
    float a = att[th*32 + t];
    int gg = (g & ~7) | ((g & 7) ^ (t & 7));
    bf16x8 kv = *(const bf16x8*)(rp + (size_t)t*1024 + gg*8);
    #pragma unroll
    for (int j=0;j<8;j++) acc[j] += a*bf2f(kv[j]);
  }
  float* o = ctxp + ((((size_t)sel*BB + b)*16) + s*2 + th)*1024 + g*8;
  float4 o0, o1;
  o0.x=acc[0]; o0.y=acc[1]; o0.z=acc[2]; o0.w=acc[3];
  o1.x=acc[4]; o1.y=acc[5]; o1.z=acc[6]; o1.w=acc[7];
  ((float4*)o)[0] = o0; ((float4*)o)[1] = o1;
}

// ---------------- K6: ctx reduce -> ctxe f32 (for pgen) + xb bf16 slices ----------------
__global__ __launch_bounds__(256) void k_ctxred(const float* __restrict__ ctxp,
                                                float* __restrict__ ctx_e,
                                                short* __restrict__ xb){
  int id = blockIdx.x*256 + threadIdx.x;
  int sel = id >> 16; int rem = id & 65535; int b = rem >> 10; int d = rem & 1023;
  const float* p = ctxp + (((size_t)sel*BB + b)*16)*1024 + d;
  float s = 0.f;
  #pragma unroll
  for (int i=0;i<16;i++) s += p[i*1024];
  if (sel==0) ctx_e[(size_t)b*HIDD + d] = s;
  xb[(size_t)b*3584 + 512 + sel*1024 + d] = f2bfs(s);
}

// ---------------- K7: LSTM cell (16-slot partial reduce) + bf16 h_new ----------------
__global__ __launch_bounds__(256) void k_lstm(const float* __restrict__ gp,
                                              const float* __restrict__ b_ih,
                                              const float* __restrict__ b_hh,
                                              const float* __restrict__ c_old,
                                              float* __restrict__ out,
                                              short* __restrict__ hb){
  int id = blockIdx.x*256 + threadIdx.x;    // 65536
  int b = id >> 10, j = id & 1023;
  size_t base = (size_t)b*G4;
  float gs[4];
  #pragma unroll
  for (int g=0; g<4; g++){
    int col = g*1024 + j;
    float s = b_ih[col] + b_hh[col];
    #pragma unroll
    for (int k=0;k<16;k++) s += gp[(size_t)k*(64*G4) + base + col];
    gs[g] = s;
  }
  float ig = sigmoid_f(gs[0]);
  float fg = sigmoid_f(gs[1]);
  float gg = tanhf(gs[2]);
  float og = sigmoid_f(gs[3]);
  float cn = fg*c_old[id] + ig*gg;
  float hn = og*tanhf(cn);
  out[(size_t)BB*VSZ + id] = hn;
  out[(size_t)BB*VSZ + (size_t)BB*HIDD + id] = cn;
  hb[id] = f2bfs(hn);
}

// ---------------- K8: vocab logits via MFMA, N=128/block (250 blocks) ----------------
__global__ __launch_bounds__(256) void k_vocab2(const short* __restrict__ hb,
                                                const float* __restrict__ Wp,
                                                const float* __restrict__ bp,
                                                float* __restrict__ out){
  int tid = threadIdx.x, l = tid & 63, w = tid >> 6;
  int l15 = l & 15, l4 = l >> 4;
  int mh = w >> 1;
  int n0 = blockIdx.x*128 + (w&1)*64;
  f32x4 acc[2][4];
  #pragma unroll
  for (int i=0;i<2;i++)
    #pragma unroll
    for (int j=0;j<4;j++)
      #pragma unroll
      for (int r=0;r<4;r++) acc[i][j][r]=0.f;
  #pragma unroll 2
  for (int d0=0; d0<1024; d0+=32){
    bf16x8 af[2];
    #pragma unroll
    for (int ms=0; ms<2; ms++)
      af[ms] = *(const bf16x8*)(hb + (size_t)(mh*32 + ms*16 + l15)*1024 + d0 + l4*8);
    bf16x8 bfr[4];
    #pragma unroll
    for (int ni=0; ni<4; ni++){
      const float* bpp = Wp + (size_t)(n0 + ni*16 + l15)*1024 + d0 + l4*8;
      float4 f0 = ((const float4*)bpp)[0], f1 = ((const float4*)bpp)[1];
      bfr[ni] = cvt8(f0, f1);
    }
    #pragma unroll
    for (int ms=0; ms<2; ms++)
      #pragma unroll
      for (int ni=0; ni<4; ni++)
        acc[ms][ni] = __builtin_amdgcn_mfma_f32_16x16x32_bf16(af[ms], bfr[ni], acc[ms][ni], 0,0,0);
  }
  #pragma unroll
  for (int ms=0; ms<2; ms++)
    #pragma unroll
    for (int ni=0; ni<4; ni++)
      #pragma unroll
      for (int r=0; r<4; r++){
        int m = mh*32 + ms*16 + l4*4 + r;
        int n = n0 + ni*16 + l15;
        out[(size_t)m*VSZ + n] = acc[ms][ni][r] + bp[n];
      }
}

// ---------------- K9b: per-segment max + sumexp partials (seg<4); seg==4 blocks do p_gen ----------------
__global__ __launch_bounds__(256) void k_vred(const float* __restrict__ out,
                                              const float* __restrict__ ctxe,
                                              const float* __restrict__ tab,
                                              const int* __restrict__ y,
                                              const float* __restrict__ wc,
                                              const float* __restrict__ wsv,
                                              const float* __restrict__ wy,
                                              const float* __restrict__ pgb,
                                              float* __restrict__ vm,
                                              float* __restrict__ vs,
                                              float* __restrict__ pgen_ws){
  __shared__ float red[8];
  int b = blockIdx.x, seg = blockIdx.y;
  int tid = threadIdx.x, lane = tid & 63, w = tid >> 6;
  if (seg < 4){
    const float* row = out + (size_t)b*VSZ;
    int lo = seg*8000, hi = lo + 8000;
    float m = -3.4e38f;
    for (int i=lo+tid; i<hi; i+=256) m = fmaxf(m, row[i]);
    m = wave_max(m);
    if (lane==0) red[w] = m;
    __syncthreads();
    m = fmaxf(fmaxf(red[0],red[1]), fmaxf(red[2],red[3]));
    float s = 0.f;
    for (int i=lo+tid; i<hi; i+=256) s += __expf(row[i]-m);
    s = wave_sum(s);
    if (lane==0) red[4+w] = s;
    __syncthreads();
    if (tid==0){
      vm[b*4+seg] = m;
      vs[b*4+seg] = red[4]+red[5]+red[6]+red[7];
    }
  } else {
    const float* hn = out + (size_t)BB*VSZ + (size_t)b*HIDD;
    const float* emb = tab + (size_t)y[b]*EMBD;
    float acc = 0.f;
    #pragma unroll
    for (int i=0;i<4;i++){
      int d = i*256 + tid;
      acc += ctxe[(size_t)b*HIDD + d]*wc[d] + hn[d]*wsv[d];
    }
    #pragma unroll
    for (int i=0;i<2;i++){
      int d = i*256 + tid;
      acc += emb[d]*wy[d];
    }
    acc = wave_sum(acc);
    if (lane==0) red[w] = acc;
    __syncthreads();
    if (tid==0)
      pgen_ws[b] = sigmoid_f(red[0]+red[1]+red[2]+red[3] + pgb[0]);
  }
}

// ---------------- K9c: combine partials + scale pass (256 blocks) ----------------
__global__ __launch_bounds__(256) void k_vscale(float* __restrict__ out,
                                                const float* __restrict__ vm,
                                                const float* __restrict__ vs,
                                                const float* __restrict__ pgen_ws){
  int b = blockIdx.x, seg = blockIdx.y;
  int tid = threadIdx.x;
  float m0=vm[b*4+0], m1=vm[b*4+1], m2=vm[b*4+2], m3=vm[b*4+3];
  float M = fmaxf(fmaxf(m0,m1), fmaxf(m2,m3));
  float S = vs[b*4+0]*__expf(m0-M) + vs[b*4+1]*__expf(m1-M)
          + vs[b*4+2]*__expf(m2-M) + vs[b*4+3]*__expf(m3-M);
  float scale = pgen_ws[b] / S;
  float* row = out + (size_t)b*VSZ;
  int lo = seg*8000, hi = lo + 8000;
  for (int i=lo+tid; i<hi; i+=256) row[i] = __expf(row[i]-M)*scale;
}

// ---------------- K10: pointer scatter ----------------
__global__ __launch_bounds__(256) void k_scatter(const int* __restrict__ src_ids,
                                                 const float* __restrict__ att_e,
                                                 const float* __restrict__ pgen_ws,
                                                 float* __restrict__ out){
  int id = blockIdx.x*256 + threadIdx.x;
  int b = id >> 9;
  float pg = pgen_ws[b];
  int sid = src_ids[id];
  float contrib = (1.0f - pg) * att_e[id] * (sid < VSZ ? 1.0f : 0.0f);
  int safe = sid < VSZ-1 ? sid : VSZ-1;
  atomicAdd(&out[(size_t)b*VSZ + safe], contrib);
}

extern "C" void kernel_launch(void* const* d_in, const int* in_sizes, int n_in,
                              void* d_out, int out_size, void* d_ws, size_t ws_size,
                              hipStream_t stream){
  const int*   y     = (const int*)d_in[0];
  const float* h     = (const float*)d_in[1];
  const float* c     = (const float*)d_in[2];
  const float* enc   = (const float*)d_in[3];
  const float* bwd   = (const float*)d_in[4];
  const int*   sids  = (const int*)d_in[5];
  const int*   smask = (const int*)d_in[6];
  const float* tab   = (const float*)d_in[7];
  const float* W_ih  = (const float*)d_in[8];
  const float* W_hh  = (const float*)d_in[9];
  const float* b_ih  = (const float*)d_in[10];
  const float* b_hh  = (const float*)d_in[11];
  const float* Wq_e  = (const float*)d_in[12];
  const float* Wk_e  = (const float*)d_in[13];
  const float* v_e   = (const float*)d_in[14];
  const float* Wq_b  = (const float*)d_in[15];
  const float* Wk_b  = (const float*)d_in[16];
  const float* v_b   = (const float*)d_in[17];
  const float* Wp    = (const float*)d_in[18];
  const float* bp    = (const float*)d_in[19];
  const float* wc    = (const float*)d_in[20];
  const float* wsv   = (const float*)d_in[21];
  const float* wy    = (const float*)d_in[22];
  const float* pgb   = (const float*)d_in[23];
  float* out = (float*)d_out;

  float* W = (float*)d_ws;
  float* ws_qpe  = W; W += 8*BB*HIDD;        // qproj partials (8 K-split slots)
  float* ws_qpb  = W; W += 8*BB*HIDD;
  float* ws_ep   = W; W += 2*8*BB*TSEQ;      // energy partials [att][8][b][t]
  float* ws_atte = W; W += BB*TSEQ;
  float* ws_attb = W; W += BB*TSEQ;
  float* ws_ctxe = W; W += BB*HIDD;
  float* ws_ctxp = W; W += 2*BB*16*1024;     // 2097152 (16 slots)
  float* ws_pgen = W; W += 64;
  float* ws_vm   = W; W += 256;
  float* ws_vs   = W; W += 256;
  float* ws_gp   = W; W += 16*BB*G4;         // 4194304 (16 K-split slots)
  short* xb      = (short*)W; W += (BB*3584)/2;
  short* hb      = (short*)W; W += (BB*HIDD)/2;
  short* pk_e    = (short*)W; W += (HIDD*HIDD)/2;   // packed+swizzled Wk_e bf16
  short* pk_b    = (short*)W; W += (HIDD*HIDD)/2;
  short* pkeys   = (short*)W; W += (2*BB*TSEQ*HIDD)/2;  // 128 MB packed bf16 keys

  k_prep_all<<<33840, 256, 0, stream>>>(Wk_e, Wk_b, enc, bwd, h, tab, y,
      pk_e, pk_b, pkeys, xb);
  // qproj: K=1024 split 8 -> 64 blocks, slot stride 64*1024
  k_mm64<<<dim3(4,8,2), 256, 0, stream>>>(
      xb+2560, 3584, Wq_e, 1024, 1024, ws_qpe, 1024,
      xb+2560, 3584, Wq_b, 1024, 1024, ws_qpb, 1024);
  k_energy<<<4096, 256, 0, stream>>>(pkeys, pk_e, pk_b,
      ws_qpe, ws_qpb, v_e, v_b, ws_ep);
  k_softmax_t<<<dim3(BB,2), 256, 0, stream>>>(ws_ep, smask, ws_atte, ws_attb);
  k_ctx<<<dim3(BB,2,8), 256, 0, stream>>>(pkeys, ws_atte, ws_attb, ws_ctxp);
  k_ctxred<<<512, 256, 0, stream>>>(ws_ctxp, ws_ctxe, xb);
  // gates: z0 x@W_ih^T (K=2560, 8 splits -> slots 0-7); z1 h@W_hh^T (K=1024, 8 splits -> slots 8-15)
  k_mm64<<<dim3(16,8,2), 256, 0, stream>>>(
      xb,      3584, W_ih, 2560, 2560, ws_gp,             G4,
      xb+2560, 3584, W_hh, 1024, 1024, ws_gp + 8*BB*G4,   G4);
  k_lstm<<<256, 256, 0, stream>>>(ws_gp, b_ih, b_hh, c, out, hb);
  k_vocab2<<<250, 256, 0, stream>>>(hb, Wp, bp, out);
  k_vred<<<dim3(BB,5), 256, 0, stream>>>(out, ws_ctxe, tab, y, wc, wsv, wy, pgb,
      ws_vm, ws_vs, ws_pgen);
  k_vscale<<<dim3(BB,4), 256, 0, stream>>>(out, ws_vm, ws_vs, ws_pgen);
  k_scatter<<<128, 256, 0, stream>>>(sids, ws_atte, ws_pgen, out);
}